// Round 14
// baseline (71.226 us; speedup 1.0000x reference)
//
#include <hip/hip_runtime.h>
#include <hip/hip_cooperative_groups.h>

namespace cg = cooperative_groups;

#define CC 8
#define HW 4096
#define L2E 1.4426950408889634f
#define NG 256

// ws float offsets
#define GRAM_OFF 0         // [256][44] per-block Gram/rowsum partials
#define BMIN_OFF 11264     // [256] per-block pq min
#define BMAX_OFF 11520     // [256] per-block pq max
#define PQ_OFF   12288     // [4][4096] pq
#define KVQ_OFF  28672     // [4][4096] f32x4 {pk*log2e, pk, pv, pv*pk}
#define TAB_OFF  94208     // [4][256]  f32x4 {G, G', F, F'}

typedef __attribute__((ext_vector_type(4))) float f32x4;

static __device__ __forceinline__ float dpp_sum64(float v) {
#define DPPSTEP(CTRL, RM, BM)                                              \
  v += __int_as_float(__builtin_amdgcn_update_dpp(                         \
      0, __float_as_int(v), CTRL, RM, BM, true));
  DPPSTEP(0x111, 0xf, 0xf)   // row_shr:1
  DPPSTEP(0x112, 0xf, 0xf)   // row_shr:2
  DPPSTEP(0x114, 0xf, 0xe)   // row_shr:4
  DPPSTEP(0x118, 0xf, 0xc)   // row_shr:8
  DPPSTEP(0x142, 0xa, 0xf)   // row_bcast:15
  DPPSTEP(0x143, 0xc, 0xf)   // row_bcast:31
#undef DPPSTEP
  return v;                  // total in lane 63
}

// Cooperative single node: 256 blocks x 512 threads.
//  A: block (b,g): pq/kvq + Gram partials + pq min/max for its 64-px slice
//  ---- grid.sync ----
//  B: block (b,pg): 4 table points, m distributed over 8 waves (coalesced)
//  ---- grid.sync ----
//  C: block (b,tile): stage table, Hermite interp per pixel, CAM + epilogue
__global__ __launch_bounds__(512) void kCoop(
    const float* __restrict__ x,
    const float* __restrict__ cwq, const float* __restrict__ cbq,
    const float* __restrict__ cwk, const float* __restrict__ cbk,
    const float* __restrict__ cwv, const float* __restrict__ cbv,
    const float* __restrict__ pwq, const float* __restrict__ pbq,
    const float* __restrict__ pwk, const float* __restrict__ pbk,
    const float* __restrict__ pwv, const float* __restrict__ pbv,
    float* __restrict__ ws, float* __restrict__ out)
{
  const int blk = blockIdx.x;
  const int b = blk >> 6, g = blk & 63;
  const int t = threadIdx.x, ln = t & 63;
  const int wid = __builtin_amdgcn_readfirstlane(t >> 6);   // wave 0..7

  __shared__ f32x4 tbl[NG];                                 // 4 KB
  __shared__ float part[8][16];
  __shared__ float stats[2];
  __shared__ float sums[44], Gl[64], Ll[64], Al[64], Mp[64], cvs[8], outp[64];

  const float* xb = x + b * CC * HW;
  f32x4* KVQ4 = ((f32x4*)(ws + KVQ_OFF));

  // ================= Phase A (wave 0 only) =================
  if (t < 64) {
    const int n = g * 64 + ln;
    float xv[CC];
    #pragma unroll
    for (int c = 0; c < CC; ++c) xv[c] = xb[c * HW + n];

    float pq = pbq[0], pk = pbk[0], pv = pbv[0];
    #pragma unroll
    for (int c = 0; c < CC; ++c) {
      pq = fmaf(pwq[c], xv[c], pq);
      pk = fmaf(pwk[c], xv[c], pk);
      pv = fmaf(pwv[c], xv[c], pv);
    }
    ws[PQ_OFF + b * HW + n] = pq;
    f32x4 kq; kq[0] = pk * L2E; kq[1] = pk; kq[2] = pv; kq[3] = pv * pk;
    KVQ4[b * HW + n] = kq;

    float acc[44];
    {
      int k = 0;
      #pragma unroll
      for (int c = 0; c < CC; ++c) {
        #pragma unroll
        for (int d = c; d < CC; ++d) { acc[k] = xv[c] * xv[d]; ++k; }
      }
      #pragma unroll
      for (int c = 0; c < CC; ++c) acc[36 + c] = xv[c];
    }
    #pragma unroll
    for (int i = 0; i < 44; ++i) acc[i] = dpp_sum64(acc[i]);
    if (ln == 63) {
      #pragma unroll
      for (int i = 0; i < 44; ++i) ws[GRAM_OFF + blk * 44 + i] = acc[i];
    }

    float mn = pq, mx = pq;
    #pragma unroll
    for (int off = 32; off > 0; off >>= 1) {
      mn = fminf(mn, __shfl_xor(mn, off, 64));
      mx = fmaxf(mx, __shfl_xor(mx, off, 64));
    }
    if (ln == 0) { ws[BMIN_OFF + blk] = mn; ws[BMAX_OFF + blk] = mx; }
  }

  cg::this_grid().sync();

  // ================= Phase B =================
  // global pq range (wave 0 computes, LDS-broadcast to the block)
  if (t < 64) {
    float mn = fminf(fminf(ws[BMIN_OFF + ln],       ws[BMIN_OFF + ln + 64]),
                     fminf(ws[BMIN_OFF + ln + 128], ws[BMIN_OFF + ln + 192]));
    float mx = fmaxf(fmaxf(ws[BMAX_OFF + ln],       ws[BMAX_OFF + ln + 64]),
                     fmaxf(ws[BMAX_OFF + ln + 128], ws[BMAX_OFF + ln + 192]));
    #pragma unroll
    for (int off = 32; off > 0; off >>= 1) {
      mn = fminf(mn, __shfl_xor(mn, off, 64));
      mx = fmaxf(mx, __shfl_xor(mx, off, 64));
    }
    if (ln == 0) {
      const float smin = mn - 1e-4f;
      stats[0] = smin;
      stats[1] = fmaxf(mx + 1e-4f - smin, 1e-3f) / (float)(NG - 1);
    }
  }
  __syncthreads();
  const float smin = stats[0], delta = stats[1];

  {
    const int pg = g;                                  // 4 points: pg*4..pg*4+3
    float s[4];
    #pragma unroll
    for (int j = 0; j < 4; ++j) s[j] = smin + delta * (float)(pg * 4 + j);

    float G[4] = {0, 0, 0, 0}, P[4] = {0, 0, 0, 0};
    float F[4] = {0, 0, 0, 0}, Q[4] = {0, 0, 0, 0};
    #pragma unroll
    for (int i = 0; i < 8; ++i) {
      const f32x4 q = KVQ4[b * HW + wid * 512 + i * 64 + ln];  // coalesced
      #pragma unroll
      for (int j = 0; j < 4; ++j) {
        const float e = __builtin_amdgcn_exp2f(s[j] * q[0]);
        G[j] += e;
        P[j] = fmaf(q[1], e, P[j]);
        F[j] = fmaf(q[2], e, F[j]);
        Q[j] = fmaf(q[3], e, Q[j]);
      }
    }
    float red[16];
    #pragma unroll
    for (int j = 0; j < 4; ++j) {
      red[j * 4 + 0] = dpp_sum64(G[j]);
      red[j * 4 + 1] = dpp_sum64(P[j]);
      red[j * 4 + 2] = dpp_sum64(F[j]);
      red[j * 4 + 3] = dpp_sum64(Q[j]);
    }
    if (ln == 63) {
      #pragma unroll
      for (int i = 0; i < 16; ++i) part[wid][i] = red[i];
    }
    __syncthreads();
    if (t < 16) {
      float v = 0.f;
      #pragma unroll
      for (int w = 0; w < 8; ++w) v += part[w][t];
      ws[TAB_OFF + (b * NG + pg * 4 + (t >> 2)) * 4 + (t & 3)] = v;
    }
  }

  cg::this_grid().sync();

  // ================= Phase C =================
  const int n0 = g * 64;

  if (t < 256) tbl[t] = ((const f32x4*)(ws + TAB_OFF))[b * NG + t];
  if (t < 44) {
    float sm = 0.f;
    for (int j = 0; j < 64; ++j) sm += ws[GRAM_OFF + (b * 64 + j) * 44 + t];
    sums[t] = sm;
  }
  __syncthreads();

  const int c = ln >> 3, d = ln & 7;
  if (t < 64) {
    const int lo = min(c, d), hi = max(c, d);
    Gl[t] = sums[lo * 8 + hi - lo * (lo + 1) / 2];
  }
  __syncthreads();

  float Lv = 0.f;
  if (t < 64) {
    float qs = 0.f, ks = 0.f;
    #pragma unroll
    for (int e = 0; e < 8; ++e) {
      qs = fmaf(cwq[c * 8 + e], sums[36 + e], qs);
      ks = fmaf(cwk[d * 8 + e], sums[36 + e], ks);
    }
    float A = 0.f;
    #pragma unroll
    for (int e = 0; e < 8; ++e) {
      float inner = 0.f;
      #pragma unroll
      for (int f = 0; f < 8; ++f) inner = fmaf(Gl[e * 8 + f], cwk[d * 8 + f], inner);
      A = fmaf(cwq[c * 8 + e], inner, A);
    }
    Lv = A + qs * cbk[d] + cbq[c] * ks + 4096.f * cbq[c] * cbk[d];
    Ll[t] = Lv;
  }
  __syncthreads();

  if (t < 64) {
    float mx = -INFINITY;
    #pragma unroll
    for (int f = 0; f < 8; ++f) mx = fmaxf(mx, Ll[c * 8 + f]);
    float ssum = 0.f;
    #pragma unroll
    for (int f = 0; f < 8; ++f) ssum += __expf(Ll[c * 8 + f] - mx);
    Al[t] = __expf(Lv - mx) / ssum;
  }
  __syncthreads();

  if (t < 64) {
    float M = 0.f;
    #pragma unroll
    for (int f = 0; f < 8; ++f) M = fmaf(Al[c * 8 + f], cwv[f * 8 + d], M);
    if (d == c) M += 2.f;            // +2I: residual x appears in both CAM and PAM
    Mp[t] = M;
    if (d == 0) {
      float cvv = 0.f;
      #pragma unroll
      for (int f = 0; f < 8; ++f) cvv = fmaf(Al[c * 8 + f], cbv[f], cvv);
      cvs[c] = cvv;
    }
  }

  // per-pixel Hermite interp (wave 0; needs only tbl + pq)
  if (t < 64) {
    const float pqn = ws[PQ_OFF + b * HW + n0 + ln];
    float u = (pqn - smin) / delta;
    u = fminf(fmaxf(u, 0.f), (float)(NG - 1));
    int i0 = (int)u;
    i0 = min(i0, NG - 2);
    const float tf = u - (float)i0;
    const f32x4 c0 = tbl[i0], c1 = tbl[i0 + 1];
    const float omt = 1.f - tf;
    const float omt2 = omt * omt, t2 = tf * tf;
    const float h00 = (1.f + 2.f * tf) * omt2;
    const float h10 = tf * omt2;
    const float h01 = t2 * (3.f - 2.f * tf);
    const float h11 = t2 * (tf - 1.f);
    const float Gv = h00 * c0[0] + h10 * delta * c0[1] + h01 * c1[0] + h11 * delta * c1[1];
    const float Fv = h00 * c0[2] + h10 * delta * c0[3] + h01 * c1[2] + h11 * delta * c1[3];
    outp[ln] = Fv / Gv;
  }
  __syncthreads();

  // epilogue: thread t -> channel t>>6, pixel n0 + (t&63)
  {
    const int ch = t >> 6, px = t & 63;
    float xn[CC];
    #pragma unroll
    for (int dd = 0; dd < CC; ++dd) xn[dd] = xb[dd * HW + n0 + px];
    float o = cvs[ch] + outp[px];
    #pragma unroll
    for (int dd = 0; dd < CC; ++dd) o = fmaf(Mp[ch * 8 + dd], xn[dd], o);
    out[(b * 8 + ch) * HW + n0 + px] = o;
  }
}

extern "C" void kernel_launch(void* const* d_in, const int* in_sizes, int n_in,
                              void* d_out, int out_size, void* d_ws, size_t ws_size,
                              hipStream_t stream) {
  const float* x   = (const float*)d_in[0];
  const float* cwq = (const float*)d_in[1];
  const float* cbq = (const float*)d_in[2];
  const float* cwk = (const float*)d_in[3];
  const float* cbk = (const float*)d_in[4];
  const float* cwv = (const float*)d_in[5];
  const float* cbv = (const float*)d_in[6];
  const float* pwq = (const float*)d_in[7];
  const float* pbq = (const float*)d_in[8];
  const float* pwk = (const float*)d_in[9];
  const float* pbk = (const float*)d_in[10];
  const float* pwv = (const float*)d_in[11];
  const float* pbv = (const float*)d_in[12];
  float* ws  = (float*)d_ws;
  float* out = (float*)d_out;

  void* args[] = {
    (void*)&x,
    (void*)&cwq, (void*)&cbq, (void*)&cwk, (void*)&cbk, (void*)&cwv, (void*)&cbv,
    (void*)&pwq, (void*)&pbq, (void*)&pwk, (void*)&pbk, (void*)&pwv, (void*)&pbv,
    (void*)&ws, (void*)&out,
  };
  hipLaunchCooperativeKernel((const void*)kCoop, dim3(256), dim3(512),
                             args, 0, stream);
}

// Round 15
// 20.403 us; speedup vs baseline: 3.4910x; 3.4910x over previous
//
#include <hip/hip_runtime.h>

#define CC 8
#define HW 4096
#define L2E 1.4426950408889634f

typedef __attribute__((ext_vector_type(4))) float f32x4;
typedef __attribute__((ext_vector_type(2))) float f32x2;

// Full-wave (64-lane) sum reduction on the VALU pipe via DPP (lands in lane 63).
static __device__ __forceinline__ float dpp_sum64(float v) {
#define DPPSTEP(CTRL, RM, BM)                                              \
  v += __int_as_float(__builtin_amdgcn_update_dpp(                         \
      0, __float_as_int(v), CTRL, RM, BM, true));
  DPPSTEP(0x111, 0xf, 0xf)   // row_shr:1
  DPPSTEP(0x112, 0xf, 0xf)   // row_shr:2
  DPPSTEP(0x114, 0xf, 0xe)   // row_shr:4
  DPPSTEP(0x118, 0xf, 0xc)   // row_shr:8
  DPPSTEP(0x142, 0xa, 0xf)   // row_bcast:15
  DPPSTEP(0x143, 0xc, 0xf)   // row_bcast:31
#undef DPPSTEP
  return v;
}

// Rotate a value one lane across the full 64-lane wave (DPP wave_ror:1).
// All lanes have valid sources, so direction/bound_ctrl don't affect
// correctness of the 64-round full cycle below.
static __device__ __forceinline__ float wave_ror1(float v) {
  return __int_as_float(__builtin_amdgcn_update_dpp(
      0, __float_as_int(v), 0x13C /*wave_ror:1*/, 0xF, 0xF, true));
}

// Packed 2-m PAM step: v_pk_mul (arg) + 2x v_exp + v_pk_add (den) + v_pk_fma (num).
static __device__ __forceinline__ void step2(f32x2 kk, f32x2 vv, f32x2 aa,
                                             f32x2& dd, f32x2& nn) {
  f32x2 arg = aa * kk;                        // v_pk_mul_f32
  f32x2 ee;
  ee[0] = __builtin_amdgcn_exp2f(arg[0]);
  ee[1] = __builtin_amdgcn_exp2f(arg[1]);
  dd += ee;                                   // v_pk_add_f32
  nn = __builtin_elementwise_fma(ee, vv, nn); // v_pk_fma_f32
}

// Single node: 256 blocks (4 batches x 64-pixel tiles) x 512 threads (8 waves).
// P2 is a register-systolic rotation: lane l keeps its own 8 m's (k2,v) in
// the registers that produced them (wave w's lanes hold exactly m in
// [512w,512w+512)); the accumulator triple (a,den,num) rotates through all
// 64 lanes via DPP wave_ror:1. Zero LDS / zero waitcnt in the hot loop --
// trans-pipe bound at the exp floor (R12's ~18us kernel was latency-stalled
// on the LDS broadcast feed at 2 waves/SIMD).
__global__ __launch_bounds__(512) void kFused(
    const float* __restrict__ x,
    const float* __restrict__ cwq, const float* __restrict__ cbq,
    const float* __restrict__ cwk, const float* __restrict__ cbk,
    const float* __restrict__ cwv, const float* __restrict__ cbv,
    const float* __restrict__ pwq, const float* __restrict__ pbq,
    const float* __restrict__ pwk, const float* __restrict__ pbk,
    const float* __restrict__ pwv, const float* __restrict__ pbv,
    float* __restrict__ out)
{
  const int b = blockIdx.x >> 6, tile = blockIdx.x & 63;
  const int n0 = tile * 64;
  const int t = threadIdx.x, ln = t & 63;
  const int wid = __builtin_amdgcn_readfirstlane(t >> 6);   // wave 0..7

  __shared__ float redd[8][64], redn[8][64];                // 4 KB
  __shared__ float gpart[8][44];
  __shared__ float sums[44], Gl[64], Ll[64], Al[64], Mp[64], cvs[8], outp[64];

  const float* xb = x + b * CC * HW;

  // ---- P0a: (k2,v) for my 8 m's (m = 8t..8t+7), kept in registers ----
  f32x4 xa[CC], xc[CC];
  f32x4 ka, kb, va, vb;                       // k2 x8, v x8 (adjacent pairs)
  {
    const int m8 = t * 8;
    #pragma unroll
    for (int c = 0; c < CC; ++c) {
      xa[c] = *(const f32x4*)(xb + c * HW + m8);
      xc[c] = *(const f32x4*)(xb + c * HW + m8 + 4);
    }
    #pragma unroll
    for (int j = 0; j < 8; ++j) {
      float kk = pbk[0], vv = pbv[0];
      #pragma unroll
      for (int c = 0; c < CC; ++c) {
        const float xv = (j < 4) ? xa[c][j & 3] : xc[c][j & 3];
        kk = fmaf(pwk[c], xv, kk);
        vv = fmaf(pwv[c], xv, vv);
      }
      kk *= L2E;
      if (j < 4) { ka[j] = kk; va[j] = vv; }
      else       { kb[j & 3] = kk; vb[j & 3] = vv; }
    }
  }

  // ---- P0b: Gram + rowsum partials from the already-loaded registers ----
  {
    float acc[44];
    #pragma unroll
    for (int i = 0; i < 44; ++i) acc[i] = 0.f;
    #pragma unroll
    for (int j = 0; j < 8; ++j) {
      float xv[CC];
      #pragma unroll
      for (int c = 0; c < CC; ++c) xv[c] = (j < 4) ? xa[c][j & 3] : xc[c][j & 3];
      int k = 0;
      #pragma unroll
      for (int c = 0; c < CC; ++c) {
        #pragma unroll
        for (int d = c; d < CC; ++d) { acc[k] = fmaf(xv[c], xv[d], acc[k]); ++k; }
      }
      #pragma unroll
      for (int c = 0; c < CC; ++c) acc[36 + c] += xv[c];
    }
    #pragma unroll
    for (int i = 0; i < 44; ++i) acc[i] = dpp_sum64(acc[i]);
    if (ln == 63) {
      #pragma unroll
      for (int i = 0; i < 44; ++i) gpart[wid][i] = acc[i];   // static idx
    }
  }

  // ---- P0c: pq + xn for pixel n0+ln ----
  float xn[CC];
  #pragma unroll
  for (int c = 0; c < CC; ++c) xn[c] = xb[c * HW + n0 + ln];
  float a = pbq[0];
  #pragma unroll
  for (int c = 0; c < CC; ++c) a = fmaf(pwq[c], xn[c], a);

  // ---- P2: systolic PAM; (a,den,num) rotates, (k2,v) stays put ----
  {
    float den = 0.f, num = 0.f;
    #pragma unroll 4
    for (int r = 0; r < 64; ++r) {
      f32x2 aa; aa[0] = a; aa[1] = a;
      f32x2 dd; dd[0] = 0.f; dd[1] = 0.f;
      f32x2 nn = dd;
      f32x2 kk, vv;
      kk[0] = ka[0]; kk[1] = ka[1]; vv[0] = va[0]; vv[1] = va[1];
      step2(kk, vv, aa, dd, nn);
      kk[0] = ka[2]; kk[1] = ka[3]; vv[0] = va[2]; vv[1] = va[3];
      step2(kk, vv, aa, dd, nn);
      kk[0] = kb[0]; kk[1] = kb[1]; vv[0] = vb[0]; vv[1] = vb[1];
      step2(kk, vv, aa, dd, nn);
      kk[0] = kb[2]; kk[1] = kb[3]; vv[0] = vb[2]; vv[1] = vb[3];
      step2(kk, vv, aa, dd, nn);
      den += dd[0] + dd[1];
      num += nn[0] + nn[1];
      // rotate the accumulator triple; after 64 rotations it is home again
      a   = wave_ror1(a);
      den = wave_ror1(den);
      num = wave_ror1(num);
    }
    redd[wid][ln] = den;
    redn[wid][ln] = num;
  }
  __syncthreads();

  // ---- P3: wave 0: PAM combine + Gram total + CAM 8x8 softmax ----
  if (t < 64) {
    float D = 0.f, N = 0.f;
    #pragma unroll
    for (int s = 0; s < 8; ++s) { D += redd[s][t]; N += redn[s][t]; }
    outp[t] = N / D;
  }
  if (t < 44) {
    float s = 0.f;
    #pragma unroll
    for (int w = 0; w < 8; ++w) s += gpart[w][t];
    sums[t] = s;
  }
  __syncthreads();

  const int c = ln >> 3, d = ln & 7;
  if (t < 64) {
    const int lo = min(c, d), hi = max(c, d);
    Gl[t] = sums[lo * 8 + hi - lo * (lo + 1) / 2];
  }
  __syncthreads();

  float Lv = 0.f;
  if (t < 64) {
    float qs = 0.f, ks = 0.f;
    #pragma unroll
    for (int e = 0; e < 8; ++e) {
      qs = fmaf(cwq[c * 8 + e], sums[36 + e], qs);
      ks = fmaf(cwk[d * 8 + e], sums[36 + e], ks);
    }
    float A = 0.f;
    #pragma unroll
    for (int e = 0; e < 8; ++e) {
      float inner = 0.f;
      #pragma unroll
      for (int f = 0; f < 8; ++f) inner = fmaf(Gl[e * 8 + f], cwk[d * 8 + f], inner);
      A = fmaf(cwq[c * 8 + e], inner, A);
    }
    Lv = A + qs * cbk[d] + cbq[c] * ks + 4096.f * cbq[c] * cbk[d];
    Ll[t] = Lv;
  }
  __syncthreads();

  if (t < 64) {
    float mx = -INFINITY;
    #pragma unroll
    for (int f = 0; f < 8; ++f) mx = fmaxf(mx, Ll[c * 8 + f]);
    float ssum = 0.f;
    #pragma unroll
    for (int f = 0; f < 8; ++f) ssum += __expf(Ll[c * 8 + f] - mx);
    Al[t] = __expf(Lv - mx) / ssum;
  }
  __syncthreads();

  if (t < 64) {
    float M = 0.f;
    #pragma unroll
    for (int f = 0; f < 8; ++f) M = fmaf(Al[c * 8 + f], cwv[f * 8 + d], M);
    if (d == c) M += 2.f;            // +2I: residual x appears in both CAM and PAM
    Mp[t] = M;
    if (d == 0) {
      float cvv = 0.f;
      #pragma unroll
      for (int f = 0; f < 8; ++f) cvv = fmaf(Al[c * 8 + f], cbv[f], cvv);
      cvs[c] = cvv;
    }
  }
  __syncthreads();

  // ---- P4: epilogue, thread (wid, ln) -> channel wid, pixel n0+ln ----
  {
    float o = cvs[wid] + outp[ln];
    #pragma unroll
    for (int dd2 = 0; dd2 < 8; ++dd2) o = fmaf(Mp[wid * 8 + dd2], xn[dd2], o);
    out[(b * 8 + wid) * HW + n0 + ln] = o;
  }
}

extern "C" void kernel_launch(void* const* d_in, const int* in_sizes, int n_in,
                              void* d_out, int out_size, void* d_ws, size_t ws_size,
                              hipStream_t stream) {
  const float* x   = (const float*)d_in[0];
  const float* cwq = (const float*)d_in[1];
  const float* cbq = (const float*)d_in[2];
  const float* cwk = (const float*)d_in[3];
  const float* cbk = (const float*)d_in[4];
  const float* cwv = (const float*)d_in[5];
  const float* cbv = (const float*)d_in[6];
  const float* pwq = (const float*)d_in[7];
  const float* pbq = (const float*)d_in[8];
  const float* pwk = (const float*)d_in[9];
  const float* pbk = (const float*)d_in[10];
  const float* pwv = (const float*)d_in[11];
  const float* pbv = (const float*)d_in[12];
  float* out = (float*)d_out;

  hipLaunchKernelGGL(kFused, dim3(256), dim3(512), 0, stream,
                     x, cwq, cbq, cwk, cbk, cwv, cbv,
                     pwq, pbq, pwk, pbk, pwv, pbv, out);
}

// Round 16
// 20.264 us; speedup vs baseline: 3.5150x; 1.0069x over previous
//
#include <hip/hip_runtime.h>

#define CC 8
#define HW 4096
#define L2E 1.4426950408889634f

typedef __attribute__((ext_vector_type(4))) float f32x4;
typedef __attribute__((ext_vector_type(2))) float f32x2;

// Full-wave (64-lane) sum reduction on the VALU pipe via DPP (lands in lane 63).
static __device__ __forceinline__ float dpp_sum64(float v) {
#define DPPSTEP(CTRL, RM, BM)                                              \
  v += __int_as_float(__builtin_amdgcn_update_dpp(                         \
      0, __float_as_int(v), CTRL, RM, BM, true));
  DPPSTEP(0x111, 0xf, 0xf)   // row_shr:1
  DPPSTEP(0x112, 0xf, 0xf)   // row_shr:2
  DPPSTEP(0x114, 0xf, 0xe)   // row_shr:4
  DPPSTEP(0x118, 0xf, 0xc)   // row_shr:8
  DPPSTEP(0x142, 0xa, 0xf)   // row_bcast:15
  DPPSTEP(0x143, 0xc, 0xf)   // row_bcast:31
#undef DPPSTEP
  return v;
}

// Rotate a value one lane across the full 64-lane wave (DPP wave_ror:1).
static __device__ __forceinline__ float wave_ror1(float v) {
  return __int_as_float(__builtin_amdgcn_update_dpp(
      0, __float_as_int(v), 0x13C /*wave_ror:1*/, 0xF, 0xF, true));
}

// Packed 2-m PAM step: v_pk_mul (arg) + 2x v_exp + v_pk_add (den) + v_pk_fma (num).
static __device__ __forceinline__ void step2(f32x2 kk, f32x2 vv, f32x2 aa,
                                             f32x2& dd, f32x2& nn) {
  f32x2 arg = aa * kk;                        // v_pk_mul_f32
  f32x2 ee;
  ee[0] = __builtin_amdgcn_exp2f(arg[0]);
  ee[1] = __builtin_amdgcn_exp2f(arg[1]);
  dd += ee;                                   // v_pk_add_f32
  nn = __builtin_elementwise_fma(ee, vv, nn); // v_pk_fma_f32
}

// Single node: 256 blocks (4 batches x 64-pixel tiles) x 512 threads (8 waves).
// R15 structure (register-systolic P2) with the serial tail parallelized:
//  - wave 0 runs the whole CAM chain BARRIER-FREE (intra-wave LDS dataflow
//    is ordered by the per-wave DS queue; barriers are only for cross-wave)
//  - wave 1 concurrently does the PAM num/den combine
//  - only 2 block-wide __syncthreads remain (was 6)
__global__ __launch_bounds__(512) void kFused(
    const float* __restrict__ x,
    const float* __restrict__ cwq, const float* __restrict__ cbq,
    const float* __restrict__ cwk, const float* __restrict__ cbk,
    const float* __restrict__ cwv, const float* __restrict__ cbv,
    const float* __restrict__ pwq, const float* __restrict__ pbq,
    const float* __restrict__ pwk, const float* __restrict__ pbk,
    const float* __restrict__ pwv, const float* __restrict__ pbv,
    float* __restrict__ out)
{
  const int b = blockIdx.x >> 6, tile = blockIdx.x & 63;
  const int n0 = tile * 64;
  const int t = threadIdx.x, ln = t & 63;
  const int wid = __builtin_amdgcn_readfirstlane(t >> 6);   // wave 0..7

  __shared__ float redd[8][64], redn[8][64];                // 4 KB
  __shared__ float gpart[8][44];
  __shared__ float sums[44], Gl[64], Ll[64], Al[64], Mp[64], cvs[8], outp[64];

  const float* xb = x + b * CC * HW;

  // ---- P0a: (k2,v) for my 8 m's (m = 8t..8t+7), kept in registers ----
  f32x4 xa[CC], xc[CC];
  f32x4 ka, kb, va, vb;                       // k2 x8, v x8
  float xn[CC];
  {
    const int m8 = t * 8;
    #pragma unroll
    for (int c = 0; c < CC; ++c) {
      xa[c] = *(const f32x4*)(xb + c * HW + m8);
      xc[c] = *(const f32x4*)(xb + c * HW + m8 + 4);
    }
    // issue the epilogue-pixel loads early; consumed after P0b
    #pragma unroll
    for (int c = 0; c < CC; ++c) xn[c] = xb[c * HW + n0 + ln];

    #pragma unroll
    for (int j = 0; j < 8; ++j) {
      float kk = pbk[0], vv = pbv[0];
      #pragma unroll
      for (int c = 0; c < CC; ++c) {
        const float xv = (j < 4) ? xa[c][j & 3] : xc[c][j & 3];
        kk = fmaf(pwk[c], xv, kk);
        vv = fmaf(pwv[c], xv, vv);
      }
      kk *= L2E;
      if (j < 4) { ka[j] = kk; va[j] = vv; }
      else       { kb[j & 3] = kk; vb[j & 3] = vv; }
    }
  }

  // ---- P0b: Gram + rowsum partials from the already-loaded registers ----
  {
    float acc[44];
    #pragma unroll
    for (int i = 0; i < 44; ++i) acc[i] = 0.f;
    #pragma unroll
    for (int j = 0; j < 8; ++j) {
      float xv[CC];
      #pragma unroll
      for (int c = 0; c < CC; ++c) xv[c] = (j < 4) ? xa[c][j & 3] : xc[c][j & 3];
      int k = 0;
      #pragma unroll
      for (int c = 0; c < CC; ++c) {
        #pragma unroll
        for (int d = c; d < CC; ++d) { acc[k] = fmaf(xv[c], xv[d], acc[k]); ++k; }
      }
      #pragma unroll
      for (int c = 0; c < CC; ++c) acc[36 + c] += xv[c];
    }
    #pragma unroll
    for (int i = 0; i < 44; ++i) acc[i] = dpp_sum64(acc[i]);
    if (ln == 63) {
      #pragma unroll
      for (int i = 0; i < 44; ++i) gpart[wid][i] = acc[i];   // static idx
    }
  }

  // ---- P0c: pq for pixel n0+ln ----
  float a = pbq[0];
  #pragma unroll
  for (int c = 0; c < CC; ++c) a = fmaf(pwq[c], xn[c], a);

  // ---- P2: systolic PAM; (a,den,num) rotates, (k2,v) stays put ----
  {
    float den = 0.f, num = 0.f;
    #pragma unroll 4
    for (int r = 0; r < 64; ++r) {
      f32x2 aa; aa[0] = a; aa[1] = a;
      a = wave_ror1(a);                       // next-round a: off critical path
      f32x2 dd; dd[0] = 0.f; dd[1] = 0.f;
      f32x2 nn = dd;
      f32x2 kk, vv;
      kk[0] = ka[0]; kk[1] = ka[1]; vv[0] = va[0]; vv[1] = va[1];
      step2(kk, vv, aa, dd, nn);
      kk[0] = ka[2]; kk[1] = ka[3]; vv[0] = va[2]; vv[1] = va[3];
      step2(kk, vv, aa, dd, nn);
      kk[0] = kb[0]; kk[1] = kb[1]; vv[0] = vb[0]; vv[1] = vb[1];
      step2(kk, vv, aa, dd, nn);
      kk[0] = kb[2]; kk[1] = kb[3]; vv[0] = vb[2]; vv[1] = vb[3];
      step2(kk, vv, aa, dd, nn);
      den += dd[0] + dd[1];
      num += nn[0] + nn[1];
      den = wave_ror1(den);
      num = wave_ror1(num);
    }
    redd[wid][ln] = den;
    redn[wid][ln] = num;
  }
  __syncthreads();                            // B1: partials visible

  // ---- P3: wave 0 = CAM chain (barrier-free); wave 1 = PAM combine ----
  if (wid == 0) {
    if (ln < 44) {
      float s = 0.f;
      #pragma unroll
      for (int w = 0; w < 8; ++w) s += gpart[w][ln];
      sums[ln] = s;
    }
    const int c = ln >> 3, d = ln & 7;
    {
      const int lo = min(c, d), hi = max(c, d);
      Gl[ln] = sums[lo * 8 + hi - lo * (lo + 1) / 2];
    }
    float qs = 0.f, ks = 0.f;
    #pragma unroll
    for (int e = 0; e < 8; ++e) {
      qs = fmaf(cwq[c * 8 + e], sums[36 + e], qs);
      ks = fmaf(cwk[d * 8 + e], sums[36 + e], ks);
    }
    float A = 0.f;
    #pragma unroll
    for (int e = 0; e < 8; ++e) {
      float inner = 0.f;
      #pragma unroll
      for (int f = 0; f < 8; ++f) inner = fmaf(Gl[e * 8 + f], cwk[d * 8 + f], inner);
      A = fmaf(cwq[c * 8 + e], inner, A);
    }
    const float Lv = A + qs * cbk[d] + cbq[c] * ks + 4096.f * cbq[c] * cbk[d];
    Ll[ln] = Lv;

    float mx = -INFINITY;
    #pragma unroll
    for (int f = 0; f < 8; ++f) mx = fmaxf(mx, Ll[c * 8 + f]);
    float ssum = 0.f;
    #pragma unroll
    for (int f = 0; f < 8; ++f) ssum += __expf(Ll[c * 8 + f] - mx);
    Al[ln] = __expf(Lv - mx) / ssum;

    float M = 0.f;
    #pragma unroll
    for (int f = 0; f < 8; ++f) M = fmaf(Al[c * 8 + f], cwv[f * 8 + d], M);
    if (d == c) M += 2.f;            // +2I: residual x appears in both CAM and PAM
    Mp[ln] = M;
    if (d == 0) {
      float cvv = 0.f;
      #pragma unroll
      for (int f = 0; f < 8; ++f) cvv = fmaf(Al[c * 8 + f], cbv[f], cvv);
      cvs[c] = cvv;
    }
  } else if (wid == 1) {
    float D = 0.f, N = 0.f;
    #pragma unroll
    for (int s = 0; s < 8; ++s) { D += redd[s][ln]; N += redn[s][ln]; }
    outp[ln] = N / D;
  }
  __syncthreads();                            // B2: Mp/cvs/outp visible

  // ---- P4: epilogue, thread (wid, ln) -> channel wid, pixel n0+ln ----
  {
    float o = cvs[wid] + outp[ln];
    #pragma unroll
    for (int dd2 = 0; dd2 < 8; ++dd2) o = fmaf(Mp[wid * 8 + dd2], xn[dd2], o);
    out[(b * 8 + wid) * HW + n0 + ln] = o;
  }
}

extern "C" void kernel_launch(void* const* d_in, const int* in_sizes, int n_in,
                              void* d_out, int out_size, void* d_ws, size_t ws_size,
                              hipStream_t stream) {
  const float* x   = (const float*)d_in[0];
  const float* cwq = (const float*)d_in[1];
  const float* cbq = (const float*)d_in[2];
  const float* cwk = (const float*)d_in[3];
  const float* cbk = (const float*)d_in[4];
  const float* cwv = (const float*)d_in[5];
  const float* cbv = (const float*)d_in[6];
  const float* pwq = (const float*)d_in[7];
  const float* pbq = (const float*)d_in[8];
  const float* pwk = (const float*)d_in[9];
  const float* pbk = (const float*)d_in[10];
  const float* pwv = (const float*)d_in[11];
  const float* pbv = (const float*)d_in[12];
  float* out = (float*)d_out;

  hipLaunchKernelGGL(kFused, dim3(256), dim3(512), 0, stream,
                     x, cwq, cbq, cwk, cbk, cwv, cbv,
                     pwq, pbq, pwk, pbk, pwv, pbv, out);
}